// Round 8
// baseline (984.401 us; speedup 1.0000x reference)
//
#include <hip/hip_runtime.h>

#define NN 100000
#define NE 1600000
#define NADJ 2
#define NLAY 3
#define HD 128
#define NG 1024

#define SCAN_BLOCKS ((NN + 255) / 256)   // 391

typedef unsigned int uint32;
typedef unsigned short u16;

typedef __attribute__((ext_vector_type(8))) short bfrag8;   // 8 bf16 (4 VGPR)
typedef __attribute__((ext_vector_type(4))) float f32x4;

__device__ __forceinline__ u16 f2bf(float f) {   // RNE pack
    uint32 u = __float_as_uint(f);
    u += 0x7FFFu + ((u >> 16) & 1u);
    return (u16)(u >> 16);
}
__device__ __forceinline__ float bflo(uint32 u) { return __uint_as_float(u << 16); }
__device__ __forceinline__ float bfhi(uint32 u) { return __uint_as_float(u & 0xFFFF0000u); }

// x (fp32) -> bf16, 8 elems/thread; grid covers NN*HD/8 EXACTLY (6250 blocks)
__global__ __launch_bounds__(256) void to_bf16(const float* __restrict__ in,
                                               u16* __restrict__ o) {
    int i = blockIdx.x * 256 + threadIdx.x;
    float4 a = ((const float4*)in)[i * 2];
    float4 b = ((const float4*)in)[i * 2 + 1];
    uint4 v;
    v.x = (uint32)f2bf(a.x) | ((uint32)f2bf(a.y) << 16);
    v.y = (uint32)f2bf(a.z) | ((uint32)f2bf(a.w) << 16);
    v.z = (uint32)f2bf(b.x) | ((uint32)f2bf(b.y) << 16);
    v.w = (uint32)f2bf(b.z) | ((uint32)f2bf(b.w) << 16);
    ((uint4*)o)[i] = v;
}

// one-time: wt[b][n][k] = bf16(W_b[k][n]); b in [0,6) -> conv, b==6 -> lin0_w
__global__ void wt_prep(const float* __restrict__ conv_w,
                        const float* __restrict__ lin0_w, u16* __restrict__ wt) {
    const float* W = (blockIdx.x < 6) ? conv_w + (size_t)blockIdx.x * HD * HD
                                      : lin0_w;
    u16* o = wt + (size_t)blockIdx.x * HD * HD;
    for (int i = 0; i < 64; ++i) {
        int idx = i * 256 + threadIdx.x;
        int n = idx >> 7, k = idx & 127;
        o[idx] = f2bf(W[k * 128 + n]);
    }
}

// ---------------- MFMA GEMM, LDS-free: out = bf16( post( A @ W ) ) ----------
// Each wave owns a 64x64 output tile (rowtile = wid>>1, colhalf = wid&1).
// A rows have zero cross-wave reuse -> load fragments direct from global;
// B (32 KB) is L1/L2-resident. No LDS, no barriers.
__global__ __launch_bounds__(256) void gemm_mfma(
    const u16* __restrict__ Abf, const u16* __restrict__ Wt,
    u16* __restrict__ outbf, const float* __restrict__ dis,
    const float* __restrict__ bias, int relu)
{
    const int wid = blockIdx.x * 4 + (threadIdx.x >> 6);
    const int lane = threadIdx.x & 63;
    const int row0 = (wid >> 1) * 64;
    if (row0 >= NN) return;
    const int wc = (wid & 1) * 64;
    const int lr = lane & 15, kg = lane >> 4;

    // preload all B fragments (reused across the 4 row-frags)
    bfrag8 b[4][4];
    #pragma unroll
    for (int ks = 0; ks < 4; ++ks)
        #pragma unroll
        for (int j = 0; j < 4; ++j)
            b[ks][j] = *(const bfrag8*)&Wt[(size_t)(wc + j * 16 + lr) * 128
                                           + (ks * 4 + kg) * 8];

    const f32x4 z = {0.f, 0.f, 0.f, 0.f};
    f32x4 acc[4][4];
    #pragma unroll
    for (int i = 0; i < 4; ++i)
        #pragma unroll
        for (int j = 0; j < 4; ++j) acc[i][j] = z;

    #pragma unroll
    for (int ks = 0; ks < 4; ++ks) {          // K = 4 x 32
        bfrag8 a[4];
        #pragma unroll
        for (int i = 0; i < 4; ++i) {
            int r = min(row0 + i * 16 + lr, NN - 1);   // tail clamp
            a[i] = *(const bfrag8*)&Abf[(size_t)r * 128 + (ks * 4 + kg) * 8];
        }
        #pragma unroll
        for (int i = 0; i < 4; ++i)
            #pragma unroll
            for (int j = 0; j < 4; ++j)
                acc[i][j] = __builtin_amdgcn_mfma_f32_16x16x32_bf16(
                    a[i], b[ks][j], acc[i][j], 0, 0, 0);
    }

    // C/D: col = lane&15, row = (lane>>4)*4 + reg   [m89-verified]
    #pragma unroll
    for (int i = 0; i < 4; ++i) {
        #pragma unroll
        for (int r = 0; r < 4; ++r) {
            int grow = row0 + i * 16 + kg * 4 + r;
            if (grow < NN) {
                float ds = dis ? dis[grow] : 1.f;
                #pragma unroll
                for (int j = 0; j < 4; ++j) {
                    int gcol = wc + j * 16 + lr;
                    float o = acc[i][j][r] * ds;
                    if (bias) o += bias[gcol];
                    if (relu) o = fmaxf(o, 0.f);
                    outbf[(size_t)grow * 128 + gcol] = f2bf(o);
                }
            }
        }
    }
}

// histogram of col + per-edge local offset (old count), coalesced write
__global__ void hist_plocal(const int* __restrict__ col,
                            int* __restrict__ cnt, int* __restrict__ p_local) {
    int e = blockIdx.x * 256 + threadIdx.x;
    if (e < NE) p_local[e] = atomicAdd(&cnt[col[e]], 1);
}

// ---- hierarchical scan: cnt -> row_ptr (exclusive), dis = rsqrt(cnt+1)

__global__ __launch_bounds__(256) void block_sums(
    const int* __restrict__ cnt, int* __restrict__ bsum)
{
    __shared__ int ws[4];
    int i = blockIdx.x * 256 + threadIdx.x;
    int v = (i < NN) ? cnt[i] : 0;
    #pragma unroll
    for (int off = 32; off > 0; off >>= 1) v += __shfl_xor(v, off);
    int wid = threadIdx.x >> 6;
    if ((threadIdx.x & 63) == 0) ws[wid] = v;
    __syncthreads();
    if (threadIdx.x == 0) bsum[blockIdx.x] = ws[0] + ws[1] + ws[2] + ws[3];
}

__global__ __launch_bounds__(512) void scan_bsums(int* __restrict__ bsum)
{
    __shared__ int s[512];
    int t = threadIdx.x;
    int v = (t < SCAN_BLOCKS) ? bsum[t] : 0;
    s[t] = v;
    __syncthreads();
    #pragma unroll
    for (int off = 1; off < 512; off <<= 1) {
        int u = (t >= off) ? s[t - off] : 0;
        __syncthreads();
        s[t] += u;
        __syncthreads();
    }
    if (t < SCAN_BLOCKS) bsum[t] = s[t] - v;   // exclusive
}

__global__ __launch_bounds__(256) void write_rowptr(
    const int* __restrict__ cnt, const int* __restrict__ bsum,
    int* __restrict__ row_ptr, float* __restrict__ dis)
{
    __shared__ int s[256];
    int t = threadIdx.x;
    int i = blockIdx.x * 256 + t;
    int v = (i < NN) ? cnt[i] : 0;
    s[t] = v;
    __syncthreads();
    #pragma unroll
    for (int off = 1; off < 256; off <<= 1) {
        int u = (t >= off) ? s[t - off] : 0;
        __syncthreads();
        s[t] += u;
        __syncthreads();
    }
    if (i < NN) {
        int excl = bsum[blockIdx.x] + s[t] - v;
        row_ptr[i] = excl;
        dis[i] = rsqrtf((float)(v + 1));   // +1 self loop
        if (i == NN - 1) row_ptr[NN] = excl + v;
    }
}

// atomic-free scatter: slot = row_ptr[col] + p_local
__global__ void scatter_edges(
    const int* __restrict__ row, const int* __restrict__ col,
    const int* __restrict__ p_local, const int* __restrict__ row_ptr,
    int* __restrict__ csr_src)
{
    int e = blockIdx.x * 256 + threadIdx.x;
    if (e >= NE) return;
    csr_src[row_ptr[col[e]] + p_local[e]] = row[e];
}

// out[i] = bf16( relu( dis[i] * ( mm[i] + sum_e mm[src_e] ) ) ), one wave/node.
// UN=32 -> 32 independent 256B row-gathers in flight per wave.
__global__ __launch_bounds__(256) void agg_relu(
    const u16* __restrict__ mm, const int* __restrict__ row_ptr,
    const int* __restrict__ csr_src,
    const float* __restrict__ dis, u16* __restrict__ out)
{
    int node = blockIdx.x * 4 + (threadIdx.x >> 6);
    if (node >= NN) return;
    int lane = threadIdx.x & 63;
    const uint32* mv = (const uint32*)mm;
    uint32 self = mv[(size_t)node * 64 + lane];
    float accx = bflo(self);
    float accy = bfhi(self);
    int e0 = row_ptr[node], e1 = row_ptr[node + 1];

    #define UN 32
    int e = e0;
    for (; e + UN <= e1; e += UN) {
        int ss[UN];
        #pragma unroll
        for (int u = 0; u < UN; ++u) ss[u] = csr_src[e + u];
        uint32 vv[UN];
        #pragma unroll
        for (int u = 0; u < UN; ++u)
            vv[u] = mv[(size_t)ss[u] * 64 + lane];
        #pragma unroll
        for (int u = 0; u < UN; ++u) {
            accx += bflo(vv[u]);
            accy += bfhi(vv[u]);
        }
    }
    if (e < e1) {   // masked tail (clamped dupes are L1 hits)
        int ss[UN];
        float mk[UN];
        #pragma unroll
        for (int u = 0; u < UN; ++u) {
            int idx = e + u;
            ss[u] = csr_src[min(idx, e1 - 1)];
            mk[u] = (idx < e1) ? 1.f : 0.f;
        }
        uint32 vv[UN];
        #pragma unroll
        for (int u = 0; u < UN; ++u)
            vv[u] = mv[(size_t)ss[u] * 64 + lane];
        #pragma unroll
        for (int u = 0; u < UN; ++u) {
            accx = fmaf(mk[u], bflo(vv[u]), accx);
            accy = fmaf(mk[u], bfhi(vv[u]), accy);
        }
    }
    #undef UN

    float d = dis[node];
    uint32 po = (uint32)f2bf(fmaxf(d * accx, 0.f))
              | ((uint32)f2bf(fmaxf(d * accy, 0.f)) << 16);
    ((uint32*)out)[(size_t)node * 64 + lane] = po;
}

// pooled[batch[n]][aoff + 2c..2c+1] += h[n][2c..2c+1]; 64 threads, uint32 loads
__global__ __launch_bounds__(64) void pool_add(
    const u16* __restrict__ h, const int* __restrict__ batch,
    float* __restrict__ pooled, int aoff)
{
    int c2 = threadIdx.x;                 // col pair
    const uint32* hv = (const uint32*)h;
    int n0 = blockIdx.x * 64;
    int nend = min(n0 + 64, NN);
    int cur = batch[n0];
    float ax = 0.f, ay = 0.f;
    for (int n = n0; n < nend; ++n) {
        int g = batch[n];
        if (g != cur) {
            atomicAdd(&pooled[(size_t)cur * 256 + aoff + 2 * c2], ax);
            atomicAdd(&pooled[(size_t)cur * 256 + aoff + 2 * c2 + 1], ay);
            ax = 0.f; ay = 0.f;
            cur = g;
        }
        uint32 v = hv[(size_t)n * 64 + c2];
        ax += bflo(v);
        ay += bfhi(v);
    }
    atomicAdd(&pooled[(size_t)cur * 256 + aoff + 2 * c2], ax);
    atomicAdd(&pooled[(size_t)cur * 256 + aoff + 2 * c2 + 1], ay);
}

// out[g] = relu(pooled[g] @ w1 + b1) @ w2 + b2
__global__ __launch_bounds__(128) void head(
    const float* __restrict__ pooled,
    const float* __restrict__ w1, const float* __restrict__ b1,
    const float* __restrict__ w2, const float* __restrict__ b2,
    float* __restrict__ out)
{
    __shared__ float sp[256];
    __shared__ float sg[128];
    int g = blockIdx.x, t = threadIdx.x;
    sp[t] = pooled[(size_t)g * 256 + t];
    sp[t + 128] = pooled[(size_t)g * 256 + 128 + t];
    __syncthreads();
    float acc = b1[t];
    #pragma unroll 8
    for (int k = 0; k < 256; ++k) acc = fmaf(sp[k], w1[k * 128 + t], acc);
    sg[t] = fmaxf(acc, 0.f) * w2[t];
    __syncthreads();
    for (int s2 = 64; s2 > 0; s2 >>= 1) {
        if (t < s2) sg[t] += sg[t + s2];
        __syncthreads();
    }
    if (t == 0) out[g] = sg[0] + b2[0];
}

extern "C" void kernel_launch(void* const* d_in, const int* in_sizes, int n_in,
                              void* d_out, int out_size, void* d_ws, size_t ws_size,
                              hipStream_t stream) {
    const float* x      = (const float*)d_in[0];
    const int*   ei     = (const int*)d_in[1];
    const int*   batch  = (const int*)d_in[2];
    const float* lin0_w = (const float*)d_in[3];
    const float* lin0_b = (const float*)d_in[4];
    const float* conv_w = (const float*)d_in[5];
    const float* lin1_w = (const float*)d_in[6];
    const float* lin1_b = (const float*)d_in[7];
    const float* lin2_w = (const float*)d_in[8];
    const float* lin2_b = (const float*)d_in[9];
    float* out = (float*)d_out;

    const size_t NB = (size_t)NN * HD;
    float* x0f    = (float*)d_ws;              // first half: x0 bf16; second: xbf
    float* bufA   = x0f + NB;                  // mm (bf16); also p_local
    float* bufB   = bufA + NB;                 // h (bf16)
    float* pooled = bufB + NB;
    int*   cnt     = (int*)(pooled + (size_t)NG * 256);
    int*   row_ptr = cnt + NN;
    float* dis     = (float*)(row_ptr + NN + 1);
    int*   csr_src = (int*)(dis + NN);
    int*   bsum    = csr_src + NE;
    u16*   wt      = (u16*)(bsum + 512);       // 7 x 128 x 128 bf16 = 224 KB

    u16* x0bf    = (u16*)x0f;                  // NB bf16 = 25.6 MB
    u16* xbf     = (u16*)(x0f + NB / 2);       // x as bf16, 25.6 MB
    u16* mm      = (u16*)bufA;
    u16* hbuf    = (u16*)bufB;
    int* p_local = (int*)bufA;   // dead before first conv gemm writes mm

    const int GEMM_BLOCKS = (((NN + 63) / 64) * 2 + 3) / 4;   // 782

    hipMemsetAsync(pooled, 0, (size_t)NG * 256 * sizeof(float), stream);

    to_bf16<<<NN * HD / 8 / 256, 256, 0, stream>>>(x, xbf);
    wt_prep<<<NADJ * NLAY + 1, 256, 0, stream>>>(conv_w, lin0_w, wt);

    // x0 = bf16(relu(x @ lin0_w + lin0_b))   via MFMA
    gemm_mfma<<<GEMM_BLOCKS, 256, 0, stream>>>(
        xbf, wt + 6 * HD * HD, x0bf, nullptr, lin0_b, 1);

    for (int a = 0; a < NADJ; ++a) {
        const int* row = ei + (size_t)a * 2 * NE;
        const int* col = row + NE;

        hipMemsetAsync(cnt, 0, NN * sizeof(int), stream);
        hist_plocal<<<(NE + 255) / 256, 256, 0, stream>>>(col, cnt, p_local);
        block_sums<<<SCAN_BLOCKS, 256, 0, stream>>>(cnt, bsum);
        scan_bsums<<<1, 512, 0, stream>>>(bsum);
        write_rowptr<<<SCAN_BLOCKS, 256, 0, stream>>>(cnt, bsum, row_ptr, dis);
        scatter_edges<<<(NE + 255) / 256, 256, 0, stream>>>(row, col, p_local,
                                                            row_ptr, csr_src);

        const u16* h = x0bf;
        for (int l = 0; l < NLAY; ++l) {
            const u16* Wt = wt + ((size_t)a * NLAY + l) * HD * HD;
            gemm_mfma<<<GEMM_BLOCKS, 256, 0, stream>>>(h, Wt, mm, dis,
                                                       nullptr, 0);
            agg_relu<<<(NN + 3) / 4, 256, 0, stream>>>(mm, row_ptr, csr_src,
                                                       dis, hbuf);
            h = hbuf;
        }
        pool_add<<<(NN + 63) / 64, 64, 0, stream>>>(hbuf, batch, pooled, a * HD);
    }

    head<<<NG, 128, 0, stream>>>(pooled, lin1_w, lin1_b, lin2_w, lin2_b, out);
}

// Round 9
// 917.724 us; speedup vs baseline: 1.0727x; 1.0727x over previous
//
#include <hip/hip_runtime.h>

#define NN 100000
#define NE 1600000
#define NADJ 2
#define NLAY 3
#define HD 128
#define NG 1024

#define SCAN_BLOCKS ((NN + 255) / 256)   // 391

typedef unsigned int uint32;
typedef unsigned short u16;

typedef __attribute__((ext_vector_type(8))) short bfrag8;   // 8 bf16 (4 VGPR)
typedef __attribute__((ext_vector_type(4))) float f32x4;

__device__ __forceinline__ u16 f2bf(float f) {   // RNE pack
    uint32 u = __float_as_uint(f);
    u += 0x7FFFu + ((u >> 16) & 1u);
    return (u16)(u >> 16);
}
__device__ __forceinline__ float bflo(uint32 u) { return __uint_as_float(u << 16); }
__device__ __forceinline__ float bfhi(uint32 u) { return __uint_as_float(u & 0xFFFF0000u); }

// x (fp32) -> bf16, 8 elems/thread; grid covers NN*HD/8 EXACTLY (6250 blocks)
__global__ __launch_bounds__(256) void to_bf16(const float* __restrict__ in,
                                               u16* __restrict__ o) {
    int i = blockIdx.x * 256 + threadIdx.x;
    float4 a = ((const float4*)in)[i * 2];
    float4 b = ((const float4*)in)[i * 2 + 1];
    uint4 v;
    v.x = (uint32)f2bf(a.x) | ((uint32)f2bf(a.y) << 16);
    v.y = (uint32)f2bf(a.z) | ((uint32)f2bf(a.w) << 16);
    v.z = (uint32)f2bf(b.x) | ((uint32)f2bf(b.y) << 16);
    v.w = (uint32)f2bf(b.z) | ((uint32)f2bf(b.w) << 16);
    ((uint4*)o)[i] = v;
}

// one-time: wt[b][n][k] = bf16(W_b[k][n]); b in [0,6) -> conv, b==6 -> lin0_w
__global__ void wt_prep(const float* __restrict__ conv_w,
                        const float* __restrict__ lin0_w, u16* __restrict__ wt) {
    const float* W = (blockIdx.x < 6) ? conv_w + (size_t)blockIdx.x * HD * HD
                                      : lin0_w;
    u16* o = wt + (size_t)blockIdx.x * HD * HD;
    for (int i = 0; i < 64; ++i) {
        int idx = i * 256 + threadIdx.x;
        int n = idx >> 7, k = idx & 127;
        o[idx] = f2bf(W[k * 128 + n]);
    }
}

// ---------------- MFMA GEMM, LDS-free: out = bf16( post( A @ W ) ) ----------
__global__ __launch_bounds__(256) void gemm_mfma(
    const u16* __restrict__ Abf, const u16* __restrict__ Wt,
    u16* __restrict__ outbf, const float* __restrict__ dis,
    const float* __restrict__ bias, int relu)
{
    const int wid = blockIdx.x * 4 + (threadIdx.x >> 6);
    const int lane = threadIdx.x & 63;
    const int row0 = (wid >> 1) * 64;
    if (row0 >= NN) return;
    const int wc = (wid & 1) * 64;
    const int lr = lane & 15, kg = lane >> 4;

    bfrag8 b[4][4];
    #pragma unroll
    for (int ks = 0; ks < 4; ++ks)
        #pragma unroll
        for (int j = 0; j < 4; ++j)
            b[ks][j] = *(const bfrag8*)&Wt[(size_t)(wc + j * 16 + lr) * 128
                                           + (ks * 4 + kg) * 8];

    const f32x4 z = {0.f, 0.f, 0.f, 0.f};
    f32x4 acc[4][4];
    #pragma unroll
    for (int i = 0; i < 4; ++i)
        #pragma unroll
        for (int j = 0; j < 4; ++j) acc[i][j] = z;

    #pragma unroll
    for (int ks = 0; ks < 4; ++ks) {          // K = 4 x 32
        bfrag8 a[4];
        #pragma unroll
        for (int i = 0; i < 4; ++i) {
            int r = min(row0 + i * 16 + lr, NN - 1);   // tail clamp
            a[i] = *(const bfrag8*)&Abf[(size_t)r * 128 + (ks * 4 + kg) * 8];
        }
        #pragma unroll
        for (int i = 0; i < 4; ++i)
            #pragma unroll
            for (int j = 0; j < 4; ++j)
                acc[i][j] = __builtin_amdgcn_mfma_f32_16x16x32_bf16(
                    a[i], b[ks][j], acc[i][j], 0, 0, 0);
    }

    // C/D: col = lane&15, row = (lane>>4)*4 + reg   [m89-verified]
    #pragma unroll
    for (int i = 0; i < 4; ++i) {
        #pragma unroll
        for (int r = 0; r < 4; ++r) {
            int grow = row0 + i * 16 + kg * 4 + r;
            if (grow < NN) {
                float ds = dis ? dis[grow] : 1.f;
                #pragma unroll
                for (int j = 0; j < 4; ++j) {
                    int gcol = wc + j * 16 + lr;
                    float o = acc[i][j][r] * ds;
                    if (bias) o += bias[gcol];
                    if (relu) o = fmaxf(o, 0.f);
                    outbf[(size_t)grow * 128 + gcol] = f2bf(o);
                }
            }
        }
    }
}

// 8-way split histogram: block b atomics into copy b&7 -> contention /8.
// p_local[e] = rank of edge e within (copy, col).
__global__ void hist_plocal(const int* __restrict__ col,
                            int* __restrict__ cnt8, int* __restrict__ p_local) {
    int e = blockIdx.x * 256 + threadIdx.x;
    if (e < NE) {
        int copy = blockIdx.x & 7;
        p_local[e] = atomicAdd(&cnt8[copy * NN + col[e]], 1);
    }
}

// per node: total cnt + per-copy exclusive offsets
__global__ __launch_bounds__(256) void combine_hist(
    const int* __restrict__ cnt8, int* __restrict__ cnt,
    int* __restrict__ copyoff) {
    int i = blockIdx.x * 256 + threadIdx.x;
    if (i >= NN) return;
    int s = 0;
    #pragma unroll
    for (int c = 0; c < 8; ++c) {
        int v = cnt8[c * NN + i];
        copyoff[c * NN + i] = s;
        s += v;
    }
    cnt[i] = s;
}

// ---- hierarchical scan: cnt -> row_ptr (exclusive), dis = rsqrt(cnt+1)

__global__ __launch_bounds__(256) void block_sums(
    const int* __restrict__ cnt, int* __restrict__ bsum)
{
    __shared__ int ws[4];
    int i = blockIdx.x * 256 + threadIdx.x;
    int v = (i < NN) ? cnt[i] : 0;
    #pragma unroll
    for (int off = 32; off > 0; off >>= 1) v += __shfl_xor(v, off);
    int wid = threadIdx.x >> 6;
    if ((threadIdx.x & 63) == 0) ws[wid] = v;
    __syncthreads();
    if (threadIdx.x == 0) bsum[blockIdx.x] = ws[0] + ws[1] + ws[2] + ws[3];
}

__global__ __launch_bounds__(512) void scan_bsums(int* __restrict__ bsum)
{
    __shared__ int s[512];
    int t = threadIdx.x;
    int v = (t < SCAN_BLOCKS) ? bsum[t] : 0;
    s[t] = v;
    __syncthreads();
    #pragma unroll
    for (int off = 1; off < 512; off <<= 1) {
        int u = (t >= off) ? s[t - off] : 0;
        __syncthreads();
        s[t] += u;
        __syncthreads();
    }
    if (t < SCAN_BLOCKS) bsum[t] = s[t] - v;   // exclusive
}

__global__ __launch_bounds__(256) void write_rowptr(
    const int* __restrict__ cnt, const int* __restrict__ bsum,
    int* __restrict__ row_ptr, float* __restrict__ dis)
{
    __shared__ int s[256];
    int t = threadIdx.x;
    int i = blockIdx.x * 256 + t;
    int v = (i < NN) ? cnt[i] : 0;
    s[t] = v;
    __syncthreads();
    #pragma unroll
    for (int off = 1; off < 256; off <<= 1) {
        int u = (t >= off) ? s[t - off] : 0;
        __syncthreads();
        s[t] += u;
        __syncthreads();
    }
    if (i < NN) {
        int excl = bsum[blockIdx.x] + s[t] - v;
        row_ptr[i] = excl;
        dis[i] = rsqrtf((float)(v + 1));   // +1 self loop
        if (i == NN - 1) row_ptr[NN] = excl + v;
    }
}

// atomic-free scatter: slot = row_ptr[col] + copyoff[copy][col] + p_local
__global__ void scatter_edges(
    const int* __restrict__ row, const int* __restrict__ col,
    const int* __restrict__ p_local, const int* __restrict__ row_ptr,
    const int* __restrict__ copyoff, int* __restrict__ csr_src)
{
    int e = blockIdx.x * 256 + threadIdx.x;
    if (e >= NE) return;
    int c = col[e];
    int copy = (e >> 8) & 7;              // must match hist_plocal's blockIdx&7
    int slot = row_ptr[c] + copyoff[copy * NN + c] + p_local[e];
    __builtin_nontemporal_store(row[e], &csr_src[slot]);
}

// out[i] = bf16( relu( dis[i] * ( mm[i] + sum_e mm[src_e] ) ) ), one wave/node.
// UN=16 matches mean degree (UN=32 was VALU-issue-bound on masked waste: R8).
__global__ __launch_bounds__(256) void agg_relu(
    const u16* __restrict__ mm, const int* __restrict__ row_ptr,
    const int* __restrict__ csr_src,
    const float* __restrict__ dis, u16* __restrict__ out)
{
    int node = blockIdx.x * 4 + (threadIdx.x >> 6);
    if (node >= NN) return;
    int lane = threadIdx.x & 63;
    const uint32* mv = (const uint32*)mm;
    uint32 self = mv[(size_t)node * 64 + lane];
    float accx = bflo(self);
    float accy = bfhi(self);
    int e0 = row_ptr[node], e1 = row_ptr[node + 1];

    #define UN 16
    int e = e0;
    for (; e + UN <= e1; e += UN) {
        int ss[UN];
        #pragma unroll
        for (int u = 0; u < UN; ++u) ss[u] = csr_src[e + u];
        uint32 vv[UN];
        #pragma unroll
        for (int u = 0; u < UN; ++u)
            vv[u] = mv[(size_t)ss[u] * 64 + lane];
        #pragma unroll
        for (int u = 0; u < UN; ++u) {
            accx += bflo(vv[u]);
            accy += bfhi(vv[u]);
        }
    }
    if (e < e1) {   // masked tail (clamped dupes are L1 hits)
        int ss[UN];
        float mk[UN];
        #pragma unroll
        for (int u = 0; u < UN; ++u) {
            int idx = e + u;
            ss[u] = csr_src[min(idx, e1 - 1)];
            mk[u] = (idx < e1) ? 1.f : 0.f;
        }
        uint32 vv[UN];
        #pragma unroll
        for (int u = 0; u < UN; ++u)
            vv[u] = mv[(size_t)ss[u] * 64 + lane];
        #pragma unroll
        for (int u = 0; u < UN; ++u) {
            accx = fmaf(mk[u], bflo(vv[u]), accx);
            accy = fmaf(mk[u], bfhi(vv[u]), accy);
        }
    }
    #undef UN

    float d = dis[node];
    uint32 po = (uint32)f2bf(fmaxf(d * accx, 0.f))
              | ((uint32)f2bf(fmaxf(d * accy, 0.f)) << 16);
    ((uint32*)out)[(size_t)node * 64 + lane] = po;
}

// pooled[batch[n]][aoff + 2c..2c+1] += h[n][2c..2c+1]; 64 threads, uint32 loads
__global__ __launch_bounds__(64) void pool_add(
    const u16* __restrict__ h, const int* __restrict__ batch,
    float* __restrict__ pooled, int aoff)
{
    int c2 = threadIdx.x;                 // col pair
    const uint32* hv = (const uint32*)h;
    int n0 = blockIdx.x * 64;
    int nend = min(n0 + 64, NN);
    int cur = batch[n0];
    float ax = 0.f, ay = 0.f;
    for (int n = n0; n < nend; ++n) {
        int g = batch[n];
        if (g != cur) {
            atomicAdd(&pooled[(size_t)cur * 256 + aoff + 2 * c2], ax);
            atomicAdd(&pooled[(size_t)cur * 256 + aoff + 2 * c2 + 1], ay);
            ax = 0.f; ay = 0.f;
            cur = g;
        }
        uint32 v = hv[(size_t)n * 64 + c2];
        ax += bflo(v);
        ay += bfhi(v);
    }
    atomicAdd(&pooled[(size_t)cur * 256 + aoff + 2 * c2], ax);
    atomicAdd(&pooled[(size_t)cur * 256 + aoff + 2 * c2 + 1], ay);
}

// out[g] = relu(pooled[g] @ w1 + b1) @ w2 + b2
__global__ __launch_bounds__(128) void head(
    const float* __restrict__ pooled,
    const float* __restrict__ w1, const float* __restrict__ b1,
    const float* __restrict__ w2, const float* __restrict__ b2,
    float* __restrict__ out)
{
    __shared__ float sp[256];
    __shared__ float sg[128];
    int g = blockIdx.x, t = threadIdx.x;
    sp[t] = pooled[(size_t)g * 256 + t];
    sp[t + 128] = pooled[(size_t)g * 256 + 128 + t];
    __syncthreads();
    float acc = b1[t];
    #pragma unroll 8
    for (int k = 0; k < 256; ++k) acc = fmaf(sp[k], w1[k * 128 + t], acc);
    sg[t] = fmaxf(acc, 0.f) * w2[t];
    __syncthreads();
    for (int s2 = 64; s2 > 0; s2 >>= 1) {
        if (t < s2) sg[t] += sg[t + s2];
        __syncthreads();
    }
    if (t == 0) out[g] = sg[0] + b2[0];
}

extern "C" void kernel_launch(void* const* d_in, const int* in_sizes, int n_in,
                              void* d_out, int out_size, void* d_ws, size_t ws_size,
                              hipStream_t stream) {
    const float* x      = (const float*)d_in[0];
    const int*   ei     = (const int*)d_in[1];
    const int*   batch  = (const int*)d_in[2];
    const float* lin0_w = (const float*)d_in[3];
    const float* lin0_b = (const float*)d_in[4];
    const float* conv_w = (const float*)d_in[5];
    const float* lin1_w = (const float*)d_in[6];
    const float* lin1_b = (const float*)d_in[7];
    const float* lin2_w = (const float*)d_in[8];
    const float* lin2_b = (const float*)d_in[9];
    float* out = (float*)d_out;

    const size_t NB = (size_t)NN * HD;
    float* x0f    = (float*)d_ws;              // first half: x0 bf16; second: xbf
    float* bufA   = x0f + NB;                  // mm (bf16); also p_local
    float* bufB   = bufA + NB;                 // h (bf16)
    float* pooled = bufB + NB;
    int*   cnt     = (int*)(pooled + (size_t)NG * 256);
    int*   row_ptr = cnt + NN;
    float* dis     = (float*)(row_ptr + NN + 1);
    int*   csr_src = (int*)(dis + NN);
    int*   bsum    = csr_src + NE;
    u16*   wt      = (u16*)(bsum + 512);       // 7 x 128 x 128 bf16 = 224 KB
    int*   cnt8    = (int*)(wt + 7 * HD * HD); // 8 x NN = 3.2 MB
    int*   copyoff = cnt8 + 8 * NN;            // 8 x NN = 3.2 MB

    u16* x0bf    = (u16*)x0f;                  // NB bf16 = 25.6 MB
    u16* xbf     = (u16*)(x0f + NB / 2);       // x as bf16, 25.6 MB
    u16* mm      = (u16*)bufA;
    u16* hbuf    = (u16*)bufB;
    int* p_local = (int*)bufA;   // dead before first conv gemm writes mm

    const int GEMM_BLOCKS = (((NN + 63) / 64) * 2 + 3) / 4;   // 782

    hipMemsetAsync(pooled, 0, (size_t)NG * 256 * sizeof(float), stream);

    to_bf16<<<NN * HD / 8 / 256, 256, 0, stream>>>(x, xbf);
    wt_prep<<<NADJ * NLAY + 1, 256, 0, stream>>>(conv_w, lin0_w, wt);

    // x0 = bf16(relu(x @ lin0_w + lin0_b))   via MFMA
    gemm_mfma<<<GEMM_BLOCKS, 256, 0, stream>>>(
        xbf, wt + 6 * HD * HD, x0bf, nullptr, lin0_b, 1);

    for (int a = 0; a < NADJ; ++a) {
        const int* row = ei + (size_t)a * 2 * NE;
        const int* col = row + NE;

        hipMemsetAsync(cnt8, 0, 8 * NN * sizeof(int), stream);
        hist_plocal<<<(NE + 255) / 256, 256, 0, stream>>>(col, cnt8, p_local);
        combine_hist<<<SCAN_BLOCKS, 256, 0, stream>>>(cnt8, cnt, copyoff);
        block_sums<<<SCAN_BLOCKS, 256, 0, stream>>>(cnt, bsum);
        scan_bsums<<<1, 512, 0, stream>>>(bsum);
        write_rowptr<<<SCAN_BLOCKS, 256, 0, stream>>>(cnt, bsum, row_ptr, dis);
        scatter_edges<<<(NE + 255) / 256, 256, 0, stream>>>(row, col, p_local,
                                                            row_ptr, copyoff,
                                                            csr_src);

        const u16* h = x0bf;
        for (int l = 0; l < NLAY; ++l) {
            const u16* Wt = wt + ((size_t)a * NLAY + l) * HD * HD;
            gemm_mfma<<<GEMM_BLOCKS, 256, 0, stream>>>(h, Wt, mm, dis,
                                                       nullptr, 0);
            agg_relu<<<(NN + 3) / 4, 256, 0, stream>>>(mm, row_ptr, csr_src,
                                                       dis, hbuf);
            h = hbuf;
        }
        pool_add<<<(NN + 63) / 64, 64, 0, stream>>>(hbuf, batch, pooled, a * HD);
    }

    head<<<NG, 128, 0, stream>>>(pooled, lin1_w, lin1_b, lin2_w, lin2_b, out);
}

// Round 10
// 887.592 us; speedup vs baseline: 1.1091x; 1.0339x over previous
//
#include <hip/hip_runtime.h>

#define NN 100000
#define NE 1600000
#define NADJ 2
#define NLAY 3
#define HD 128
#define NG 1024

#define SCAN_BLOCKS ((NN + 255) / 256)   // 391

typedef unsigned int uint32;
typedef unsigned short u16;

typedef __attribute__((ext_vector_type(8))) short bfrag8;   // 8 bf16 (4 VGPR)
typedef __attribute__((ext_vector_type(4))) float f32x4;

__device__ __forceinline__ u16 f2bf(float f) {   // RNE pack
    uint32 u = __float_as_uint(f);
    u += 0x7FFFu + ((u >> 16) & 1u);
    return (u16)(u >> 16);
}
__device__ __forceinline__ float bflo(uint32 u) { return __uint_as_float(u << 16); }
__device__ __forceinline__ float bfhi(uint32 u) { return __uint_as_float(u & 0xFFFF0000u); }

// x (fp32) -> bf16, 8 elems/thread; grid covers NN*HD/8 EXACTLY (6250 blocks)
__global__ __launch_bounds__(256) void to_bf16(const float* __restrict__ in,
                                               u16* __restrict__ o) {
    int i = blockIdx.x * 256 + threadIdx.x;
    float4 a = ((const float4*)in)[i * 2];
    float4 b = ((const float4*)in)[i * 2 + 1];
    uint4 v;
    v.x = (uint32)f2bf(a.x) | ((uint32)f2bf(a.y) << 16);
    v.y = (uint32)f2bf(a.z) | ((uint32)f2bf(a.w) << 16);
    v.z = (uint32)f2bf(b.x) | ((uint32)f2bf(b.y) << 16);
    v.w = (uint32)f2bf(b.z) | ((uint32)f2bf(b.w) << 16);
    ((uint4*)o)[i] = v;
}

// one-time: wt[b][n][k] = bf16(W_b[k][n]); b in [0,6) -> conv, b==6 -> lin0_w
__global__ void wt_prep(const float* __restrict__ conv_w,
                        const float* __restrict__ lin0_w, u16* __restrict__ wt) {
    const float* W = (blockIdx.x < 6) ? conv_w + (size_t)blockIdx.x * HD * HD
                                      : lin0_w;
    u16* o = wt + (size_t)blockIdx.x * HD * HD;
    for (int i = 0; i < 64; ++i) {
        int idx = i * 256 + threadIdx.x;
        int n = idx >> 7, k = idx & 127;
        o[idx] = f2bf(W[k * 128 + n]);
    }
}

// ---------------- MFMA GEMM, LDS-free: out = bf16( post( A @ W ) ) ----------
__global__ __launch_bounds__(256) void gemm_mfma(
    const u16* __restrict__ Abf, const u16* __restrict__ Wt,
    u16* __restrict__ outbf, const float* __restrict__ dis,
    const float* __restrict__ bias, int relu)
{
    const int wid = blockIdx.x * 4 + (threadIdx.x >> 6);
    const int lane = threadIdx.x & 63;
    const int row0 = (wid >> 1) * 64;
    if (row0 >= NN) return;
    const int wc = (wid & 1) * 64;
    const int lr = lane & 15, kg = lane >> 4;

    bfrag8 b[4][4];
    #pragma unroll
    for (int ks = 0; ks < 4; ++ks)
        #pragma unroll
        for (int j = 0; j < 4; ++j)
            b[ks][j] = *(const bfrag8*)&Wt[(size_t)(wc + j * 16 + lr) * 128
                                           + (ks * 4 + kg) * 8];

    const f32x4 z = {0.f, 0.f, 0.f, 0.f};
    f32x4 acc[4][4];
    #pragma unroll
    for (int i = 0; i < 4; ++i)
        #pragma unroll
        for (int j = 0; j < 4; ++j) acc[i][j] = z;

    #pragma unroll
    for (int ks = 0; ks < 4; ++ks) {          // K = 4 x 32
        bfrag8 a[4];
        #pragma unroll
        for (int i = 0; i < 4; ++i) {
            int r = min(row0 + i * 16 + lr, NN - 1);   // tail clamp
            a[i] = *(const bfrag8*)&Abf[(size_t)r * 128 + (ks * 4 + kg) * 8];
        }
        #pragma unroll
        for (int i = 0; i < 4; ++i)
            #pragma unroll
            for (int j = 0; j < 4; ++j)
                acc[i][j] = __builtin_amdgcn_mfma_f32_16x16x32_bf16(
                    a[i], b[ks][j], acc[i][j], 0, 0, 0);
    }

    // C/D: col = lane&15, row = (lane>>4)*4 + reg   [m89-verified]
    #pragma unroll
    for (int i = 0; i < 4; ++i) {
        #pragma unroll
        for (int r = 0; r < 4; ++r) {
            int grow = row0 + i * 16 + kg * 4 + r;
            if (grow < NN) {
                float ds = dis ? dis[grow] : 1.f;
                #pragma unroll
                for (int j = 0; j < 4; ++j) {
                    int gcol = wc + j * 16 + lr;
                    float o = acc[i][j][r] * ds;
                    if (bias) o += bias[gcol];
                    if (relu) o = fmaxf(o, 0.f);
                    outbf[(size_t)grow * 128 + gcol] = f2bf(o);
                }
            }
        }
    }
}

// 8-way split histogram: block b atomics into copy b&7 -> contention /8.
__global__ void hist_plocal(const int* __restrict__ col,
                            int* __restrict__ cnt8, int* __restrict__ p_local) {
    int e = blockIdx.x * 256 + threadIdx.x;
    if (e < NE) {
        int copy = blockIdx.x & 7;
        p_local[e] = atomicAdd(&cnt8[copy * NN + col[e]], 1);
    }
}

// per node: total cnt + per-copy exclusive offsets + fused block sums
__global__ __launch_bounds__(256) void combine_hist(
    const int* __restrict__ cnt8, int* __restrict__ cnt,
    int* __restrict__ copyoff, int* __restrict__ bsum) {
    __shared__ int ws[4];
    int i = blockIdx.x * 256 + threadIdx.x;
    int s = 0;
    if (i < NN) {
        #pragma unroll
        for (int c = 0; c < 8; ++c) {
            int v = cnt8[c * NN + i];
            copyoff[c * NN + i] = s;
            s += v;
        }
        cnt[i] = s;
    }
    int v = s;
    #pragma unroll
    for (int off = 32; off > 0; off >>= 1) v += __shfl_xor(v, off);
    if ((threadIdx.x & 63) == 0) ws[threadIdx.x >> 6] = v;
    __syncthreads();
    if (threadIdx.x == 0) bsum[blockIdx.x] = ws[0] + ws[1] + ws[2] + ws[3];
}

__global__ __launch_bounds__(512) void scan_bsums(int* __restrict__ bsum)
{
    __shared__ int s[512];
    int t = threadIdx.x;
    int v = (t < SCAN_BLOCKS) ? bsum[t] : 0;
    s[t] = v;
    __syncthreads();
    #pragma unroll
    for (int off = 1; off < 512; off <<= 1) {
        int u = (t >= off) ? s[t - off] : 0;
        __syncthreads();
        s[t] += u;
        __syncthreads();
    }
    if (t < SCAN_BLOCKS) bsum[t] = s[t] - v;   // exclusive
}

__global__ __launch_bounds__(256) void write_rowptr(
    const int* __restrict__ cnt, const int* __restrict__ bsum,
    int* __restrict__ row_ptr, float* __restrict__ dis)
{
    __shared__ int s[256];
    int t = threadIdx.x;
    int i = blockIdx.x * 256 + t;
    int v = (i < NN) ? cnt[i] : 0;
    s[t] = v;
    __syncthreads();
    #pragma unroll
    for (int off = 1; off < 256; off <<= 1) {
        int u = (t >= off) ? s[t - off] : 0;
        __syncthreads();
        s[t] += u;
        __syncthreads();
    }
    if (i < NN) {
        int excl = bsum[blockIdx.x] + s[t] - v;
        row_ptr[i] = excl;
        dis[i] = rsqrtf((float)(v + 1));   // +1 self loop
        if (i == NN - 1) row_ptr[NN] = excl + v;
    }
}

// atomic-free scatter: slot = row_ptr[col] + copyoff[copy][col] + p_local
__global__ void scatter_edges(
    const int* __restrict__ row, const int* __restrict__ col,
    const int* __restrict__ p_local, const int* __restrict__ row_ptr,
    const int* __restrict__ copyoff, int* __restrict__ csr_src)
{
    int e = blockIdx.x * 256 + threadIdx.x;
    if (e >= NE) return;
    int c = col[e];
    int copy = (e >> 8) & 7;              // must match hist_plocal's blockIdx&7
    int slot = row_ptr[c] + copyoff[copy * NN + c] + p_local[e];
    __builtin_nontemporal_store(row[e], &csr_src[slot]);
}

// out[i] = bf16( relu( dis[i] * ( mm[i] + sum_e mm[src_e] ) ) ), one wave/node.
// Main 16-wide exact; tail masked-16 only for rem 9..15, masked-8 for 1..8
// (halves the dummy-issue waste that made UN=32 regress in R8). 32-bit
// element indices keep address math off the mad_u64 path.
__global__ __launch_bounds__(256) void agg_relu(
    const u16* __restrict__ mm, const int* __restrict__ row_ptr,
    const int* __restrict__ csr_src,
    const float* __restrict__ dis, u16* __restrict__ out)
{
    int node = blockIdx.x * 4 + (threadIdx.x >> 6);
    if (node >= NN) return;
    uint32 lane = threadIdx.x & 63;
    const uint32* mv = (const uint32*)mm;
    uint32 self = mv[(uint32)node * 64u + lane];
    float accx = bflo(self);
    float accy = bfhi(self);
    int e0 = row_ptr[node], e1 = row_ptr[node + 1];

    int e = e0;
    for (; e + 16 <= e1; e += 16) {
        uint32 ss[16];
        #pragma unroll
        for (int u = 0; u < 16; ++u) ss[u] = (uint32)csr_src[e + u];
        uint32 vv[16];
        #pragma unroll
        for (int u = 0; u < 16; ++u)
            vv[u] = mv[ss[u] * 64u + lane];
        #pragma unroll
        for (int u = 0; u < 16; ++u) {
            accx += bflo(vv[u]);
            accy += bfhi(vv[u]);
        }
    }
    int rem = e1 - e;
    if (rem > 8) {          // 9..15: one masked 16-wide
        uint32 ss[16];
        float mk[16];
        #pragma unroll
        for (int u = 0; u < 16; ++u) {
            int idx = e + u;
            ss[u] = (uint32)csr_src[min(idx, e1 - 1)];
            mk[u] = (idx < e1) ? 1.f : 0.f;
        }
        uint32 vv[16];
        #pragma unroll
        for (int u = 0; u < 16; ++u)
            vv[u] = mv[ss[u] * 64u + lane];
        #pragma unroll
        for (int u = 0; u < 16; ++u) {
            accx = fmaf(mk[u], bflo(vv[u]), accx);
            accy = fmaf(mk[u], bfhi(vv[u]), accy);
        }
    } else if (rem > 0) {   // 1..8: one masked 8-wide
        uint32 ss[8];
        float mk[8];
        #pragma unroll
        for (int u = 0; u < 8; ++u) {
            int idx = e + u;
            ss[u] = (uint32)csr_src[min(idx, e1 - 1)];
            mk[u] = (idx < e1) ? 1.f : 0.f;
        }
        uint32 vv[8];
        #pragma unroll
        for (int u = 0; u < 8; ++u)
            vv[u] = mv[ss[u] * 64u + lane];
        #pragma unroll
        for (int u = 0; u < 8; ++u) {
            accx = fmaf(mk[u], bflo(vv[u]), accx);
            accy = fmaf(mk[u], bfhi(vv[u]), accy);
        }
    }

    float d = dis[node];
    uint32 po = (uint32)f2bf(fmaxf(d * accx, 0.f))
              | ((uint32)f2bf(fmaxf(d * accy, 0.f)) << 16);
    ((uint32*)out)[(uint32)node * 64u + lane] = po;
}

// pooled[batch[n]][aoff + 2c..2c+1] += h[n][2c..2c+1]; 64 threads, uint32 loads
__global__ __launch_bounds__(64) void pool_add(
    const u16* __restrict__ h, const int* __restrict__ batch,
    float* __restrict__ pooled, int aoff)
{
    int c2 = threadIdx.x;                 // col pair
    const uint32* hv = (const uint32*)h;
    int n0 = blockIdx.x * 64;
    int nend = min(n0 + 64, NN);
    int cur = batch[n0];
    float ax = 0.f, ay = 0.f;
    for (int n = n0; n < nend; ++n) {
        int g = batch[n];
        if (g != cur) {
            atomicAdd(&pooled[(size_t)cur * 256 + aoff + 2 * c2], ax);
            atomicAdd(&pooled[(size_t)cur * 256 + aoff + 2 * c2 + 1], ay);
            ax = 0.f; ay = 0.f;
            cur = g;
        }
        uint32 v = hv[(size_t)n * 64 + c2];
        ax += bflo(v);
        ay += bfhi(v);
    }
    atomicAdd(&pooled[(size_t)cur * 256 + aoff + 2 * c2], ax);
    atomicAdd(&pooled[(size_t)cur * 256 + aoff + 2 * c2 + 1], ay);
}

// out[g] = relu(pooled[g] @ w1 + b1) @ w2 + b2
__global__ __launch_bounds__(128) void head(
    const float* __restrict__ pooled,
    const float* __restrict__ w1, const float* __restrict__ b1,
    const float* __restrict__ w2, const float* __restrict__ b2,
    float* __restrict__ out)
{
    __shared__ float sp[256];
    __shared__ float sg[128];
    int g = blockIdx.x, t = threadIdx.x;
    sp[t] = pooled[(size_t)g * 256 + t];
    sp[t + 128] = pooled[(size_t)g * 256 + 128 + t];
    __syncthreads();
    float acc = b1[t];
    #pragma unroll 8
    for (int k = 0; k < 256; ++k) acc = fmaf(sp[k], w1[k * 128 + t], acc);
    sg[t] = fmaxf(acc, 0.f) * w2[t];
    __syncthreads();
    for (int s2 = 64; s2 > 0; s2 >>= 1) {
        if (t < s2) sg[t] += sg[t + s2];
        __syncthreads();
    }
    if (t == 0) out[g] = sg[0] + b2[0];
}

extern "C" void kernel_launch(void* const* d_in, const int* in_sizes, int n_in,
                              void* d_out, int out_size, void* d_ws, size_t ws_size,
                              hipStream_t stream) {
    const float* x      = (const float*)d_in[0];
    const int*   ei     = (const int*)d_in[1];
    const int*   batch  = (const int*)d_in[2];
    const float* lin0_w = (const float*)d_in[3];
    const float* lin0_b = (const float*)d_in[4];
    const float* conv_w = (const float*)d_in[5];
    const float* lin1_w = (const float*)d_in[6];
    const float* lin1_b = (const float*)d_in[7];
    const float* lin2_w = (const float*)d_in[8];
    const float* lin2_b = (const float*)d_in[9];
    float* out = (float*)d_out;

    const size_t NB = (size_t)NN * HD;
    float* x0f    = (float*)d_ws;              // first half: x0 bf16; second: xbf
    float* bufA   = x0f + NB;                  // mm (bf16); also p_local
    float* bufB   = bufA + NB;                 // h (bf16)
    float* pooled = bufB + NB;
    int*   cnt     = (int*)(pooled + (size_t)NG * 256);
    int*   row_ptr = cnt + NN;
    float* dis     = (float*)(row_ptr + NN + 1);
    int*   csr_src = (int*)(dis + NN);
    int*   bsum    = csr_src + NE;
    u16*   wt      = (u16*)(bsum + 512);       // 7 x 128 x 128 bf16 = 224 KB
    int*   cnt8    = (int*)(wt + 7 * HD * HD); // 8 x NN = 3.2 MB
    int*   copyoff = cnt8 + 8 * NN;            // 8 x NN = 3.2 MB

    u16* x0bf    = (u16*)x0f;                  // NB bf16 = 25.6 MB
    u16* xbf     = (u16*)(x0f + NB / 2);       // x as bf16, 25.6 MB
    u16* mm      = (u16*)bufA;
    u16* hbuf    = (u16*)bufB;
    int* p_local = (int*)bufA;   // dead before first conv gemm writes mm

    const int GEMM_BLOCKS = (((NN + 63) / 64) * 2 + 3) / 4;   // 782

    hipMemsetAsync(pooled, 0, (size_t)NG * 256 * sizeof(float), stream);

    to_bf16<<<NN * HD / 8 / 256, 256, 0, stream>>>(x, xbf);
    wt_prep<<<NADJ * NLAY + 1, 256, 0, stream>>>(conv_w, lin0_w, wt);

    // x0 = bf16(relu(x @ lin0_w + lin0_b))   via MFMA
    gemm_mfma<<<GEMM_BLOCKS, 256, 0, stream>>>(
        xbf, wt + 6 * HD * HD, x0bf, nullptr, lin0_b, 1);

    for (int a = 0; a < NADJ; ++a) {
        const int* row = ei + (size_t)a * 2 * NE;
        const int* col = row + NE;

        hipMemsetAsync(cnt8, 0, 8 * NN * sizeof(int), stream);
        hist_plocal<<<(NE + 255) / 256, 256, 0, stream>>>(col, cnt8, p_local);
        combine_hist<<<SCAN_BLOCKS, 256, 0, stream>>>(cnt8, cnt, copyoff, bsum);
        scan_bsums<<<1, 512, 0, stream>>>(bsum);
        write_rowptr<<<SCAN_BLOCKS, 256, 0, stream>>>(cnt, bsum, row_ptr, dis);
        scatter_edges<<<(NE + 255) / 256, 256, 0, stream>>>(row, col, p_local,
                                                            row_ptr, copyoff,
                                                            csr_src);

        const u16* h = x0bf;
        for (int l = 0; l < NLAY; ++l) {
            const u16* Wt = wt + ((size_t)a * NLAY + l) * HD * HD;
            gemm_mfma<<<GEMM_BLOCKS, 256, 0, stream>>>(h, Wt, mm, dis,
                                                       nullptr, 0);
            agg_relu<<<(NN + 3) / 4, 256, 0, stream>>>(mm, row_ptr, csr_src,
                                                       dis, hbuf);
            h = hbuf;
        }
        pool_add<<<(NN + 63) / 64, 64, 0, stream>>>(hbuf, batch, pooled, a * HD);
    }

    head<<<NG, 128, 0, stream>>>(pooled, lin1_w, lin1_b, lin2_w, lin2_b, out);
}